// Round 1
// baseline (1121.773 us; speedup 1.0000x reference)
//
#include <hip/hip_runtime.h>
#include <hip/hip_bf16.h>

#define N_NODES 50000
#define N_EDGES 800000
#define EDIM 64
#define NT 64            // nodes per block in MLP kernel
#define NTP 68           // padded LDS row stride (floats): +4 keeps 16B align, breaks bank alignment
#define KMAX 192

// ---------------------------------------------------------------------------
// Kernel 1: scatter-add edge features onto destination nodes (segment_sum)
// one thread = one float4 (4 dims of one edge); 16 float4 per edge
// ---------------------------------------------------------------------------
__global__ __launch_bounds__(256) void scatter_add_kernel(
    const float4* __restrict__ ef, const int* __restrict__ dst,
    float* __restrict__ hn)
{
    int i = blockIdx.x * 256 + threadIdx.x;      // over N_EDGES*16 float4s
    int e = i >> 4;
    int q = i & 15;
    if (e < N_EDGES) {
        float4 v = ef[i];
        int d = dst[e];
        float* p = hn + (size_t)d * EDIM + q * 4;
        atomicAdd(p + 0, v.x);
        atomicAdd(p + 1, v.y);
        atomicAdd(p + 2, v.z);
        atomicAdd(p + 3, v.w);
    }
}

// ---------------------------------------------------------------------------
// Kernel 2: fused 2-layer GIN MLP stack, 64 nodes per block
// LDS holds x transposed: xT[k][node] with padded stride NTP
// thread t: channels cg*4..cg*4+3 (cg = t&31), nodes ng*8..ng*8+7 (ng = t>>5)
// ---------------------------------------------------------------------------

// stage 64 k-rows for 64 nodes from global [node][64] into xT rows rowbase..+63
__device__ __forceinline__ void stage64(float* xT, const float* __restrict__ g,
                                        int node0, int rowbase, int t)
{
    #pragma unroll
    for (int rep = 0; rep < 4; ++rep) {
        int idx  = rep * 256 + t;    // 0..1023
        int node = idx >> 4;         // 0..63
        int kq   = idx & 15;         // float4 index within the 64-dim row
        int gn   = node0 + node;
        float4 v = make_float4(0.f, 0.f, 0.f, 0.f);
        if (gn < N_NODES) v = *(const float4*)(g + (size_t)gn * 64 + kq * 4);
        float* base = xT + (size_t)(rowbase + kq * 4) * NTP + node;
        base[0 * NTP] = v.x;
        base[1 * NTP] = v.y;
        base[2 * NTP] = v.z;
        base[3 * NTP] = v.w;
    }
}

template <int K>
__device__ __forceinline__ void linear_relu(const float* xT,
                                            const float* __restrict__ W,
                                            const float* __restrict__ b,
                                            int cg, int ng, float acc[4][8])
{
    #pragma unroll
    for (int j = 0; j < 4; ++j)
        #pragma unroll
        for (int i = 0; i < 8; ++i) acc[j][i] = 0.f;

    #pragma unroll 2
    for (int k = 0; k < K; ++k) {
        float4 w = *(const float4*)(W + (size_t)k * 128 + cg * 4);
        const float* xr = xT + (size_t)k * NTP + ng * 8;
        float4 xa = *(const float4*)(xr);
        float4 xb = *(const float4*)(xr + 4);
        float xn[8] = {xa.x, xa.y, xa.z, xa.w, xb.x, xb.y, xb.z, xb.w};
        float wv[4] = {w.x, w.y, w.z, w.w};
        #pragma unroll
        for (int j = 0; j < 4; ++j)
            #pragma unroll
            for (int i = 0; i < 8; ++i)
                acc[j][i] = fmaf(wv[j], xn[i], acc[j][i]);
    }

    float4 bias = *(const float4*)(b + cg * 4);
    float bv[4] = {bias.x, bias.y, bias.z, bias.w};
    #pragma unroll
    for (int j = 0; j < 4; ++j)
        #pragma unroll
        for (int i = 0; i < 8; ++i)
            acc[j][i] = fmaxf(acc[j][i] + bv[j], 0.f);
}

// write y[c][n] (this thread's 4x8 tile) into xT rows 0..127 (transposed layout)
__device__ __forceinline__ void writeback(float* xT, const float acc[4][8],
                                          int cg, int ng)
{
    #pragma unroll
    for (int j = 0; j < 4; ++j) {
        float* row = xT + (size_t)(cg * 4 + j) * NTP + ng * 8;
        *(float4*)(row)     = make_float4(acc[j][0], acc[j][1], acc[j][2], acc[j][3]);
        *(float4*)(row + 4) = make_float4(acc[j][4], acc[j][5], acc[j][6], acc[j][7]);
    }
}

__global__ __launch_bounds__(256) void gin_mlp_kernel(
    const float* __restrict__ nfeats, const float* __restrict__ hneigh,
    const float* __restrict__ W1_0, const float* __restrict__ b1_0,
    const float* __restrict__ W2_0, const float* __restrict__ b2_0,
    const float* __restrict__ W1_1, const float* __restrict__ b1_1,
    const float* __restrict__ W2_1, const float* __restrict__ b2_1,
    float* __restrict__ out)
{
    __shared__ float xT[KMAX * NTP];
    const int t     = threadIdx.x;
    const int node0 = blockIdx.x * NT;
    const int cg    = t & 31;
    const int ng    = t >> 5;

    float acc[4][8];

    // ---- x0 = [nfeats | hneigh] -> rows 0..127
    stage64(xT, nfeats, node0, 0, t);
    stage64(xT, hneigh, node0, 64, t);
    __syncthreads();

    // ---- layer 0, linear 1: relu(x0 @ W1_0 + b1_0), K=128
    linear_relu<128>(xT, W1_0, b1_0, cg, ng, acc);
    __syncthreads();                 // all reads of xT done
    writeback(xT, acc, cg, ng);      // rows 0..127 = t1
    stage64(xT, hneigh, node0, 128, t); // rows 128..191 = hneigh (for layer 1)
    __syncthreads();

    // ---- layer 0, linear 2: relu(t1 @ W2_0 + b2_0), K=128
    linear_relu<128>(xT, W2_0, b2_0, cg, ng, acc);
    __syncthreads();
    writeback(xT, acc, cg, ng);      // rows 0..127 = h (layer0 out)
    __syncthreads();

    // ---- layer 1, linear 1: relu([h|hneigh] @ W1_1 + b1_1), K=192
    linear_relu<192>(xT, W1_1, b1_1, cg, ng, acc);
    __syncthreads();
    writeback(xT, acc, cg, ng);      // rows 0..127 = t3
    __syncthreads();

    // ---- layer 1, linear 2: relu(t3 @ W2_1 + b2_1), K=128 -> global out
    linear_relu<128>(xT, W2_1, b2_1, cg, ng, acc);

    #pragma unroll
    for (int i = 0; i < 8; ++i) {
        int gn = node0 + ng * 8 + i;
        if (gn < N_NODES) {
            float4 v = make_float4(acc[0][i], acc[1][i], acc[2][i], acc[3][i]);
            *(float4*)(out + (size_t)gn * 128 + cg * 4) = v;
        }
    }
}

// ---------------------------------------------------------------------------
extern "C" void kernel_launch(void* const* d_in, const int* in_sizes, int n_in,
                              void* d_out, int out_size, void* d_ws, size_t ws_size,
                              hipStream_t stream)
{
    const float* nfeats = (const float*)d_in[0];
    const float* efeats = (const float*)d_in[1];
    const int*   dst    = (const int*)d_in[2];
    const float* W1_0   = (const float*)d_in[3];
    const float* b1_0   = (const float*)d_in[4];
    const float* W2_0   = (const float*)d_in[5];
    const float* b2_0   = (const float*)d_in[6];
    const float* W1_1   = (const float*)d_in[7];
    const float* b1_1   = (const float*)d_in[8];
    const float* W2_1   = (const float*)d_in[9];
    const float* b2_1   = (const float*)d_in[10];
    float* out    = (float*)d_out;
    float* hneigh = (float*)d_ws;   // N_NODES * 64 floats = 12.8 MB

    hipMemsetAsync(hneigh, 0, (size_t)N_NODES * EDIM * sizeof(float), stream);

    // scatter: 800000 edges * 16 float4 = 12.8M threads
    scatter_add_kernel<<<(N_EDGES * 16) / 256, 256, 0, stream>>>(
        (const float4*)efeats, dst, hneigh);

    // fused MLP: 64 nodes per block
    int nblk = (N_NODES + NT - 1) / NT;   // 782
    gin_mlp_kernel<<<nblk, 256, 0, stream>>>(
        nfeats, hneigh, W1_0, b1_0, W2_0, b2_0, W1_1, b1_1, W2_1, b2_1, out);
}

// Round 2
// 605.364 us; speedup vs baseline: 1.8531x; 1.8531x over previous
//
#include <hip/hip_runtime.h>
#include <hip/hip_bf16.h>

#define N_NODES 50000
#define N_EDGES 800000
#define EDIM 64
#define NT 64            // nodes per block in MLP kernel
#define NTP 68           // padded LDS row stride (floats)
#define KMAX 192
#define WCHUNK 32        // k-rows of W staged per LDS chunk

// ---------------------------------------------------------------------------
// Phase 1: counting sort of edges by dst, then per-node gather-sum.
// ws layout: hneigh[50000*64] f32 | offs[50000] i32 (pad to 256B) | order[800000] i32
// ---------------------------------------------------------------------------

__global__ __launch_bounds__(256) void hist_kernel(const int* __restrict__ dst,
                                                   int* __restrict__ cnt)
{
    int e = blockIdx.x * 256 + threadIdx.x;
    if (e < N_EDGES) atomicAdd(&cnt[dst[e]], 1);
}

// single-block in-place exclusive scan of cnt[0..N_NODES) (1024 threads)
__global__ __launch_bounds__(1024) void scan_kernel(int* __restrict__ cnt)
{
    __shared__ int wsum[16];
    __shared__ int srun;
    const int t = threadIdx.x, lane = t & 63, w = t >> 6;
    if (t == 0) srun = 0;
    __syncthreads();
    const int ntiles = (N_NODES + 1023) / 1024;   // 49
    for (int tile = 0; tile < ntiles; ++tile) {
        int i = tile * 1024 + t;
        int v = (i < N_NODES) ? cnt[i] : 0;
        int x = v;
        #pragma unroll
        for (int off = 1; off < 64; off <<= 1) {
            int u = __shfl_up(x, off);
            if (lane >= off) x += u;
        }
        if (lane == 63) wsum[w] = x;
        __syncthreads();
        if (w == 0) {
            int s = (lane < 16) ? wsum[lane] : 0;
            #pragma unroll
            for (int off = 1; off < 16; off <<= 1) {
                int u = __shfl_up(s, off);
                if (lane >= off) s += u;
            }
            if (lane < 16) wsum[lane] = s;     // inclusive over waves
        }
        __syncthreads();
        int waveoff = (w == 0) ? 0 : wsum[w - 1];
        int run = srun;
        int excl = run + waveoff + (x - v);
        if (i < N_NODES) cnt[i] = excl;
        __syncthreads();                        // all reads of srun/wsum done
        if (t == 1023) srun = run + wsum[15];   // wsum[15] = tile total
        __syncthreads();
    }
}

// after this kernel, offs[n] = end of node n's segment (original offs[n]+deg[n])
__global__ __launch_bounds__(256) void reorder_kernel(const int* __restrict__ dst,
                                                      int* __restrict__ offs,
                                                      int* __restrict__ order)
{
    int e = blockIdx.x * 256 + threadIdx.x;
    if (e < N_EDGES) {
        int d = dst[e];
        int p = atomicAdd(&offs[d], 1);
        order[p] = e;
    }
}

// one 64-lane wave per node; lane = channel
__global__ __launch_bounds__(256) void gather_kernel(const float* __restrict__ ef,
                                                     const int* __restrict__ offs,
                                                     const int* __restrict__ order,
                                                     float* __restrict__ hn)
{
    int node = blockIdx.x * 4 + (threadIdx.x >> 6);
    int lane = threadIdx.x & 63;
    if (node >= N_NODES) return;
    int s = (node == 0) ? 0 : offs[node - 1];
    int e = offs[node];
    float a0 = 0.f, a1 = 0.f, a2 = 0.f, a3 = 0.f;
    int j = s;
    for (; j + 4 <= e; j += 4) {
        int i0 = order[j], i1 = order[j + 1], i2 = order[j + 2], i3 = order[j + 3];
        a0 += ef[(size_t)i0 * 64 + lane];
        a1 += ef[(size_t)i1 * 64 + lane];
        a2 += ef[(size_t)i2 * 64 + lane];
        a3 += ef[(size_t)i3 * 64 + lane];
    }
    for (; j < e; ++j) a0 += ef[(size_t)order[j] * 64 + lane];
    hn[(size_t)node * 64 + lane] = (a0 + a1) + (a2 + a3);
}

// ---------------------------------------------------------------------------
// Phase 2: fused 2-layer GIN MLP stack, 64 nodes per block
// xT[k][node] in LDS (stride NTP); W staged in 16KB LDS chunks of 32 k-rows
// thread t: channels cg*4..+3 (cg=t&31), nodes ng*8..+7 (ng=t>>5)
// ---------------------------------------------------------------------------

__device__ __forceinline__ void stage64(float* xT, const float* __restrict__ g,
                                        int node0, int rowbase, int t)
{
    #pragma unroll
    for (int rep = 0; rep < 4; ++rep) {
        int idx  = rep * 256 + t;
        int node = idx >> 4;
        int kq   = idx & 15;
        int gn   = node0 + node;
        float4 v = make_float4(0.f, 0.f, 0.f, 0.f);
        if (gn < N_NODES) v = *(const float4*)(g + (size_t)gn * 64 + kq * 4);
        float* base = xT + (size_t)(rowbase + kq * 4) * NTP + node;
        base[0 * NTP] = v.x;
        base[1 * NTP] = v.y;
        base[2 * NTP] = v.z;
        base[3 * NTP] = v.w;
    }
}

template <int K>
__device__ __forceinline__ void linear_relu(const float* xT, float* wbuf,
                                            const float* __restrict__ W,
                                            const float* __restrict__ b,
                                            int cg, int ng, int t, float acc[4][8])
{
    #pragma unroll
    for (int j = 0; j < 4; ++j)
        #pragma unroll
        for (int i = 0; i < 8; ++i) acc[j][i] = 0.f;

    const float4* W4 = (const float4*)W;
    #pragma unroll
    for (int kc = 0; kc < K / WCHUNK; ++kc) {
        if (kc > 0) __syncthreads();           // prev chunk's wbuf reads done
        // stage 32x128 floats = 1024 float4, 4 per thread, coalesced
        #pragma unroll
        for (int r = 0; r < 4; ++r) {
            int fi = r * 256 + t;
            ((float4*)wbuf)[fi] = W4[kc * 1024 + fi];
        }
        __syncthreads();

        #pragma unroll 2
        for (int k2 = 0; k2 < WCHUNK; ++k2) {
            float4 w = *(const float4*)(wbuf + k2 * 128 + cg * 4);
            const float* xr = xT + (size_t)(kc * WCHUNK + k2) * NTP + ng * 8;
            float4 xa = *(const float4*)(xr);
            float4 xb = *(const float4*)(xr + 4);
            float xn[8] = {xa.x, xa.y, xa.z, xa.w, xb.x, xb.y, xb.z, xb.w};
            float wv[4] = {w.x, w.y, w.z, w.w};
            #pragma unroll
            for (int j = 0; j < 4; ++j)
                #pragma unroll
                for (int i = 0; i < 8; ++i)
                    acc[j][i] = fmaf(wv[j], xn[i], acc[j][i]);
        }
    }

    float4 bias = *(const float4*)(b + cg * 4);
    float bv[4] = {bias.x, bias.y, bias.z, bias.w};
    #pragma unroll
    for (int j = 0; j < 4; ++j)
        #pragma unroll
        for (int i = 0; i < 8; ++i)
            acc[j][i] = fmaxf(acc[j][i] + bv[j], 0.f);
}

__device__ __forceinline__ void writeback(float* xT, const float acc[4][8],
                                          int cg, int ng)
{
    #pragma unroll
    for (int j = 0; j < 4; ++j) {
        float* row = xT + (size_t)(cg * 4 + j) * NTP + ng * 8;
        *(float4*)(row)     = make_float4(acc[j][0], acc[j][1], acc[j][2], acc[j][3]);
        *(float4*)(row + 4) = make_float4(acc[j][4], acc[j][5], acc[j][6], acc[j][7]);
    }
}

__global__ __launch_bounds__(256) void gin_mlp_kernel(
    const float* __restrict__ nfeats, const float* __restrict__ hneigh,
    const float* __restrict__ W1_0, const float* __restrict__ b1_0,
    const float* __restrict__ W2_0, const float* __restrict__ b2_0,
    const float* __restrict__ W1_1, const float* __restrict__ b1_1,
    const float* __restrict__ W2_1, const float* __restrict__ b2_1,
    float* __restrict__ out)
{
    __shared__ float xT[KMAX * NTP];
    __shared__ float wbuf[WCHUNK * 128];
    const int t     = threadIdx.x;
    const int node0 = blockIdx.x * NT;
    const int cg    = t & 31;
    const int ng    = t >> 5;

    float acc[4][8];

    stage64(xT, nfeats, node0, 0, t);
    stage64(xT, hneigh, node0, 64, t);
    __syncthreads();

    linear_relu<128>(xT, wbuf, W1_0, b1_0, cg, ng, t, acc);
    __syncthreads();
    writeback(xT, acc, cg, ng);
    stage64(xT, hneigh, node0, 128, t);
    __syncthreads();

    linear_relu<128>(xT, wbuf, W2_0, b2_0, cg, ng, t, acc);
    __syncthreads();
    writeback(xT, acc, cg, ng);
    __syncthreads();

    linear_relu<192>(xT, wbuf, W1_1, b1_1, cg, ng, t, acc);
    __syncthreads();
    writeback(xT, acc, cg, ng);
    __syncthreads();

    linear_relu<128>(xT, wbuf, W2_1, b2_1, cg, ng, t, acc);

    #pragma unroll
    for (int i = 0; i < 8; ++i) {
        int gn = node0 + ng * 8 + i;
        if (gn < N_NODES) {
            float4 v = make_float4(acc[0][i], acc[1][i], acc[2][i], acc[3][i]);
            *(float4*)(out + (size_t)gn * 128 + cg * 4) = v;
        }
    }
}

// ---------------------------------------------------------------------------
extern "C" void kernel_launch(void* const* d_in, const int* in_sizes, int n_in,
                              void* d_out, int out_size, void* d_ws, size_t ws_size,
                              hipStream_t stream)
{
    const float* nfeats = (const float*)d_in[0];
    const float* efeats = (const float*)d_in[1];
    const int*   dst    = (const int*)d_in[2];
    const float* W1_0   = (const float*)d_in[3];
    const float* b1_0   = (const float*)d_in[4];
    const float* W2_0   = (const float*)d_in[5];
    const float* b2_0   = (const float*)d_in[6];
    const float* W1_1   = (const float*)d_in[7];
    const float* b1_1   = (const float*)d_in[8];
    const float* W2_1   = (const float*)d_in[9];
    const float* b2_1   = (const float*)d_in[10];
    float* out = (float*)d_out;

    char* ws = (char*)d_ws;
    float* hneigh = (float*)ws;                          // 12,800,000 B
    int*   offs   = (int*)(ws + 12800000);               // 200,000 B (+pad)
    int*   order  = (int*)(ws + 13000192);               // 3,200,000 B

    hipMemsetAsync(offs, 0, N_NODES * sizeof(int), stream);

    hist_kernel<<<(N_EDGES + 255) / 256, 256, 0, stream>>>(dst, offs);
    scan_kernel<<<1, 1024, 0, stream>>>(offs);
    reorder_kernel<<<(N_EDGES + 255) / 256, 256, 0, stream>>>(dst, offs, order);
    gather_kernel<<<(N_NODES + 3) / 4, 256, 0, stream>>>(efeats, offs, order, hneigh);

    int nblk = (N_NODES + NT - 1) / NT;
    gin_mlp_kernel<<<nblk, 256, 0, stream>>>(
        nfeats, hneigh, W1_0, b1_0, W2_0, b2_0, W1_1, b1_1, W2_1, b2_1, out);
}

// Round 3
// 470.763 us; speedup vs baseline: 2.3829x; 1.2859x over previous
//
#include <hip/hip_runtime.h>
#include <hip/hip_bf16.h>

#define N_NODES 50000
#define N_EDGES 800000
#define EDIM 64
#define NT 64              // nodes per MLP block
#define XS 200             // X LDS k-stride in bf16 elems (100 dwords: 100%32==4 -> conflict-free-ish)
#define N_TILES 49         // scan tiles of 1024 over 50000

typedef __attribute__((ext_vector_type(8))) short  bf16x8_t;
typedef __attribute__((ext_vector_type(4))) short  bf16x4_t;
typedef __attribute__((ext_vector_type(4))) float  f32x4_t;

__device__ __forceinline__ unsigned short f2bf(float f) {
    unsigned u = __float_as_uint(f);
    unsigned r = u + 0x7fff + ((u >> 16) & 1);     // RNE
    return (unsigned short)(r >> 16);
}
__device__ __forceinline__ float bf2f(unsigned short s) {
    return __uint_as_float(((unsigned)s) << 16);
}

// ---------------------------------------------------------------------------
// Phase 0: pre-split weights into hi/lo bf16, transposed to [n][k] (B-fragment friendly)
// wbuf layout (shorts): whi0[16384] wlo0[16384] whi1[16384] wlo1[16384]
//                       whi2[24576] wlo2[24576] whi3[16384] wlo3[16384]
// ---------------------------------------------------------------------------
__global__ __launch_bounds__(256) void prep_w_kernel(
    const float* __restrict__ W1_0, const float* __restrict__ W2_0,
    const float* __restrict__ W1_1, const float* __restrict__ W2_1,
    unsigned short* __restrict__ wbuf)
{
    int bid = blockIdx.x, t = threadIdx.x;
    const float* W; unsigned short *whi, *wlo; int K, idx;
    if (bid < 64)       { W = W1_0; K = 128; whi = wbuf;          wlo = wbuf + 16384;  idx = bid * 256 + t; }
    else if (bid < 128) { W = W2_0; K = 128; whi = wbuf + 32768;  wlo = wbuf + 49152;  idx = (bid - 64) * 256 + t; }
    else if (bid < 224) { W = W1_1; K = 192; whi = wbuf + 65536;  wlo = wbuf + 90112;  idx = (bid - 128) * 256 + t; }
    else                { W = W2_1; K = 128; whi = wbuf + 114688; wlo = wbuf + 131072; idx = (bid - 224) * 256 + t; }
    int k = idx >> 7, n = idx & 127;
    float w = W[idx];
    unsigned short h = f2bf(w);
    unsigned short l = f2bf(w - bf2f(h));
    whi[n * K + k] = h;
    wlo[n * K + k] = l;
}

// ---------------------------------------------------------------------------
// Phase 1: counting sort by dst + gather-sum
// ---------------------------------------------------------------------------
__global__ __launch_bounds__(256) void hist_kernel(const int* __restrict__ dst,
                                                   int* __restrict__ cnt)
{
    int e = blockIdx.x * 256 + threadIdx.x;
    if (e < N_EDGES) atomicAdd(&cnt[dst[e]], 1);
}

// multi-block scan: reduce -> spine -> apply
__global__ __launch_bounds__(1024) void scan_reduce_kernel(const int* __restrict__ cnt,
                                                           int* __restrict__ btot)
{
    __shared__ int wsum[16];
    int t = threadIdx.x, lane = t & 63, w = t >> 6;
    int i = blockIdx.x * 1024 + t;
    int v = (i < N_NODES) ? cnt[i] : 0;
    #pragma unroll
    for (int off = 32; off > 0; off >>= 1) v += __shfl_xor(v, off);
    if (lane == 0) wsum[w] = v;
    __syncthreads();
    if (w == 0) {
        int s = (lane < 16) ? wsum[lane] : 0;
        #pragma unroll
        for (int off = 32; off > 0; off >>= 1) s += __shfl_xor(s, off);
        if (lane == 0) btot[blockIdx.x] = s;
    }
}

__global__ __launch_bounds__(64) void scan_spine_kernel(int* __restrict__ btot)
{
    int l = threadIdx.x;
    int v = (l < N_TILES) ? btot[l] : 0;
    int x = v;
    #pragma unroll
    for (int off = 1; off < 64; off <<= 1) {
        int u = __shfl_up(x, off);
        if (l >= off) x += u;
    }
    if (l < N_TILES) btot[l] = x - v;   // exclusive
}

__global__ __launch_bounds__(1024) void scan_apply_kernel(int* __restrict__ cnt,
                                                          const int* __restrict__ btot)
{
    __shared__ int wsum[16];
    int t = threadIdx.x, lane = t & 63, w = t >> 6;
    int i = blockIdx.x * 1024 + t;
    int v = (i < N_NODES) ? cnt[i] : 0;
    int x = v;
    #pragma unroll
    for (int off = 1; off < 64; off <<= 1) {
        int u = __shfl_up(x, off);
        if (lane >= off) x += u;
    }
    if (lane == 63) wsum[w] = x;
    __syncthreads();
    if (w == 0) {
        int s = (lane < 16) ? wsum[lane] : 0;
        #pragma unroll
        for (int off = 1; off < 16; off <<= 1) {
            int u = __shfl_up(s, off);
            if (lane >= off) s += u;
        }
        if (lane < 16) wsum[lane] = s;
    }
    __syncthreads();
    int base = btot[blockIdx.x] + ((w == 0) ? 0 : wsum[w - 1]);
    if (i < N_NODES) cnt[i] = base + (x - v);   // exclusive prefix
}

// after this kernel, offs[n] = end of node n's segment
__global__ __launch_bounds__(256) void reorder_kernel(const int* __restrict__ dst,
                                                      int* __restrict__ offs,
                                                      int* __restrict__ order)
{
    int e = blockIdx.x * 256 + threadIdx.x;
    if (e < N_EDGES) {
        int d = dst[e];
        int p = atomicAdd(&offs[d], 1);
        order[p] = e;
    }
}

// one 64-lane wave per node; lane = channel
__global__ __launch_bounds__(256) void gather_kernel(const float* __restrict__ ef,
                                                     const int* __restrict__ offs,
                                                     const int* __restrict__ order,
                                                     float* __restrict__ hn)
{
    int node = blockIdx.x * 4 + (threadIdx.x >> 6);
    int lane = threadIdx.x & 63;
    if (node >= N_NODES) return;
    int s = (node == 0) ? 0 : offs[node - 1];
    int e = offs[node];
    float a0 = 0.f, a1 = 0.f, a2 = 0.f, a3 = 0.f;
    int j = s;
    for (; j + 4 <= e; j += 4) {
        int i0 = order[j], i1 = order[j + 1], i2 = order[j + 2], i3 = order[j + 3];
        a0 += ef[(size_t)i0 * 64 + lane];
        a1 += ef[(size_t)i1 * 64 + lane];
        a2 += ef[(size_t)i2 * 64 + lane];
        a3 += ef[(size_t)i3 * 64 + lane];
    }
    for (; j < e; ++j) a0 += ef[(size_t)order[j] * 64 + lane];
    hn[(size_t)node * 64 + lane] = (a0 + a1) + (a2 + a3);
}

// ---------------------------------------------------------------------------
// Phase 2: fused MLP via split-bf16 MFMA (16x16x32), 64 nodes/block, 4 waves.
// X in LDS as hi/lo bf16 planes [64][XS]. Wave w owns channels 32w..32w+31
// (n-tiles 2w, 2w+1) and all 4 m-tiles (64 nodes).
// MFMA layouts (guide-verified): A[m=lane&15][k=quad*8+j], B[k=quad*8+j][n=lane&15],
// C col=lane&15, row=quad*4+reg.
// ---------------------------------------------------------------------------

__device__ __forceinline__ void stage_x(short* Xhi, short* Xlo,
                                        const float* __restrict__ g,
                                        int node0, int k0, int t)
{
    #pragma unroll
    for (int rep = 0; rep < 4; ++rep) {
        int idx  = rep * 256 + t;       // 0..1023
        int node = idx >> 4;            // 0..63
        int kq   = idx & 15;            // float4 within 64-dim row
        int gn   = node0 + node;
        float4 v = make_float4(0.f, 0.f, 0.f, 0.f);
        if (gn < N_NODES) v = *(const float4*)(g + (size_t)gn * 64 + kq * 4);
        unsigned short h0 = f2bf(v.x), h1 = f2bf(v.y), h2 = f2bf(v.z), h3 = f2bf(v.w);
        bf16x4_t hv = {(short)h0, (short)h1, (short)h2, (short)h3};
        bf16x4_t lv = {(short)f2bf(v.x - bf2f(h0)), (short)f2bf(v.y - bf2f(h1)),
                       (short)f2bf(v.z - bf2f(h2)), (short)f2bf(v.w - bf2f(h3))};
        *(bf16x4_t*)(&Xhi[node * XS + k0 + kq * 4]) = hv;
        *(bf16x4_t*)(&Xlo[node * XS + k0 + kq * 4]) = lv;
    }
}

template <int KTOT, bool FINAL>
__device__ __forceinline__ void mfma_linear(short* Xhi, short* Xlo,
    const unsigned short* __restrict__ whi, const unsigned short* __restrict__ wlo,
    const float* __restrict__ bias, float* __restrict__ out, int node0, int t)
{
    const int lane = t & 63, wv = t >> 6, quad = lane >> 4, l15 = lane & 15;
    const int chb = wv * 32;

    f32x4_t acc[4][2];
    #pragma unroll
    for (int mt = 0; mt < 4; ++mt) {
        acc[mt][0] = (f32x4_t){0.f, 0.f, 0.f, 0.f};
        acc[mt][1] = (f32x4_t){0.f, 0.f, 0.f, 0.f};
    }
    float bv0 = bias[chb + l15];
    float bv1 = bias[chb + 16 + l15];

    const unsigned short* w0h = whi + (size_t)(chb + l15) * KTOT;
    const unsigned short* w0l = wlo + (size_t)(chb + l15) * KTOT;
    const unsigned short* w1h = whi + (size_t)(chb + 16 + l15) * KTOT;
    const unsigned short* w1l = wlo + (size_t)(chb + 16 + l15) * KTOT;

    #pragma unroll
    for (int ks = 0; ks < KTOT / 32; ++ks) {
        int kk = ks * 32 + quad * 8;
        bf16x8_t b0h = *(const bf16x8_t*)(w0h + kk);
        bf16x8_t b0l = *(const bf16x8_t*)(w0l + kk);
        bf16x8_t b1h = *(const bf16x8_t*)(w1h + kk);
        bf16x8_t b1l = *(const bf16x8_t*)(w1l + kk);
        #pragma unroll
        for (int mt = 0; mt < 4; ++mt) {
            bf16x8_t ah = *(const bf16x8_t*)(&Xhi[(mt * 16 + l15) * XS + kk]);
            bf16x8_t al = *(const bf16x8_t*)(&Xlo[(mt * 16 + l15) * XS + kk]);
            acc[mt][0] = __builtin_amdgcn_mfma_f32_16x16x32_bf16(ah, b0h, acc[mt][0], 0, 0, 0);
            acc[mt][0] = __builtin_amdgcn_mfma_f32_16x16x32_bf16(al, b0h, acc[mt][0], 0, 0, 0);
            acc[mt][0] = __builtin_amdgcn_mfma_f32_16x16x32_bf16(ah, b0l, acc[mt][0], 0, 0, 0);
            acc[mt][1] = __builtin_amdgcn_mfma_f32_16x16x32_bf16(ah, b1h, acc[mt][1], 0, 0, 0);
            acc[mt][1] = __builtin_amdgcn_mfma_f32_16x16x32_bf16(al, b1h, acc[mt][1], 0, 0, 0);
            acc[mt][1] = __builtin_amdgcn_mfma_f32_16x16x32_bf16(ah, b1l, acc[mt][1], 0, 0, 0);
        }
    }

    __syncthreads();    // all LDS reads of X done before overwrite

    if (!FINAL) {
        #pragma unroll
        for (int mt = 0; mt < 4; ++mt) {
            #pragma unroll
            for (int nt = 0; nt < 2; ++nt) {
                float bb = nt ? bv1 : bv0;
                int ch = chb + nt * 16 + l15;
                #pragma unroll
                for (int r = 0; r < 4; ++r) {
                    float y = fmaxf(acc[mt][nt][r] + bb, 0.f);
                    unsigned short h = f2bf(y);
                    unsigned short l = f2bf(y - bf2f(h));
                    int m = mt * 16 + quad * 4 + r;
                    Xhi[m * XS + ch] = (short)h;
                    Xlo[m * XS + ch] = (short)l;
                }
            }
        }
        __syncthreads();  // writes visible before next linear reads
    } else {
        #pragma unroll
        for (int mt = 0; mt < 4; ++mt) {
            #pragma unroll
            for (int nt = 0; nt < 2; ++nt) {
                float bb = nt ? bv1 : bv0;
                int ch = chb + nt * 16 + l15;
                #pragma unroll
                for (int r = 0; r < 4; ++r) {
                    int gn = node0 + mt * 16 + quad * 4 + r;
                    if (gn < N_NODES)
                        out[(size_t)gn * 128 + ch] = fmaxf(acc[mt][nt][r] + bb, 0.f);
                }
            }
        }
    }
}

__global__ __launch_bounds__(256) void gin_mlp_mfma_kernel(
    const float* __restrict__ nfeats, const float* __restrict__ hneigh,
    const unsigned short* __restrict__ wbuf,
    const float* __restrict__ b1_0, const float* __restrict__ b2_0,
    const float* __restrict__ b1_1, const float* __restrict__ b2_1,
    float* __restrict__ out)
{
    __shared__ short Xhi[NT * XS];
    __shared__ short Xlo[NT * XS];
    const int t = threadIdx.x;
    const int node0 = blockIdx.x * NT;

    // X0 = [nfeats | hneigh] rows k=0..127; hneigh again at k=128..191 for layer 1
    stage_x(Xhi, Xlo, nfeats, node0, 0, t);
    stage_x(Xhi, Xlo, hneigh, node0, 64, t);
    stage_x(Xhi, Xlo, hneigh, node0, 128, t);
    __syncthreads();

    mfma_linear<128, false>(Xhi, Xlo, wbuf,          wbuf + 16384,  b1_0, nullptr, node0, t);
    mfma_linear<128, false>(Xhi, Xlo, wbuf + 32768,  wbuf + 49152,  b2_0, nullptr, node0, t);
    mfma_linear<192, false>(Xhi, Xlo, wbuf + 65536,  wbuf + 90112,  b1_1, nullptr, node0, t);
    mfma_linear<128, true >(Xhi, Xlo, wbuf + 114688, wbuf + 131072, b2_1, out,     node0, t);
}

// ---------------------------------------------------------------------------
extern "C" void kernel_launch(void* const* d_in, const int* in_sizes, int n_in,
                              void* d_out, int out_size, void* d_ws, size_t ws_size,
                              hipStream_t stream)
{
    const float* nfeats = (const float*)d_in[0];
    const float* efeats = (const float*)d_in[1];
    const int*   dst    = (const int*)d_in[2];
    const float* W1_0   = (const float*)d_in[3];
    const float* b1_0   = (const float*)d_in[4];
    const float* W2_0   = (const float*)d_in[5];
    const float* b2_0   = (const float*)d_in[6];
    const float* W1_1   = (const float*)d_in[7];
    const float* b1_1   = (const float*)d_in[8];
    const float* W2_1   = (const float*)d_in[9];
    const float* b2_1   = (const float*)d_in[10];
    float* out = (float*)d_out;

    char* ws = (char*)d_ws;
    float*          hneigh = (float*)ws;                       // 12,800,000 B
    int*            offs   = (int*)(ws + 12800000);            // 200,000 B (+pad)
    int*            order  = (int*)(ws + 13000192);            // 3,200,000 B
    int*            btot   = (int*)(ws + 16200192);            // 256 B
    unsigned short* wbuf   = (unsigned short*)(ws + 16200448); // 294,912 B

    hipMemsetAsync(offs, 0, N_NODES * sizeof(int), stream);

    prep_w_kernel<<<288, 256, 0, stream>>>(W1_0, W2_0, W1_1, W2_1, wbuf);

    hist_kernel<<<(N_EDGES + 255) / 256, 256, 0, stream>>>(dst, offs);
    scan_reduce_kernel<<<N_TILES, 1024, 0, stream>>>(offs, btot);
    scan_spine_kernel<<<1, 64, 0, stream>>>(btot);
    scan_apply_kernel<<<N_TILES, 1024, 0, stream>>>(offs, btot);
    reorder_kernel<<<(N_EDGES + 255) / 256, 256, 0, stream>>>(dst, offs, order);
    gather_kernel<<<(N_NODES + 3) / 4, 256, 0, stream>>>(efeats, offs, order, hneigh);

    int nblk = (N_NODES + NT - 1) / NT;   // 782
    gin_mlp_mfma_kernel<<<nblk, 256, 0, stream>>>(
        nfeats, hneigh, wbuf, b1_0, b2_0, b1_1, b2_1, out);
}

// Round 4
// 453.832 us; speedup vs baseline: 2.4718x; 1.0373x over previous
//
#include <hip/hip_runtime.h>
#include <hip/hip_bf16.h>

#define N_NODES 50000
#define N_EDGES 800000
#define EDIM 64
#define NT 64              // nodes per MLP block
#define XS 200             // X LDS k-stride in bf16 elems
#define N_TILES 49         // scan tiles of 1024 over 50000

typedef __attribute__((ext_vector_type(8))) short  bf16x8_t;
typedef __attribute__((ext_vector_type(4))) short  bf16x4_t;
typedef __attribute__((ext_vector_type(4))) float  f32x4_t;

__device__ __forceinline__ unsigned short f2bf(float f) {
    unsigned u = __float_as_uint(f);
    unsigned r = u + 0x7fff + ((u >> 16) & 1);     // RNE
    return (unsigned short)(r >> 16);
}
__device__ __forceinline__ float bf2f(unsigned short s) {
    return __uint_as_float(((unsigned)s) << 16);
}

// ---------------------------------------------------------------------------
// Phase 0: pre-split weights into hi/lo bf16, transposed to [n][k]
// ---------------------------------------------------------------------------
__global__ __launch_bounds__(256) void prep_w_kernel(
    const float* __restrict__ W1_0, const float* __restrict__ W2_0,
    const float* __restrict__ W1_1, const float* __restrict__ W2_1,
    unsigned short* __restrict__ wbuf)
{
    int bid = blockIdx.x, t = threadIdx.x;
    const float* W; unsigned short *whi, *wlo; int K, idx;
    if (bid < 64)       { W = W1_0; K = 128; whi = wbuf;          wlo = wbuf + 16384;  idx = bid * 256 + t; }
    else if (bid < 128) { W = W2_0; K = 128; whi = wbuf + 32768;  wlo = wbuf + 49152;  idx = (bid - 64) * 256 + t; }
    else if (bid < 224) { W = W1_1; K = 192; whi = wbuf + 65536;  wlo = wbuf + 90112;  idx = (bid - 128) * 256 + t; }
    else                { W = W2_1; K = 128; whi = wbuf + 114688; wlo = wbuf + 131072; idx = (bid - 224) * 256 + t; }
    int k = idx >> 7, n = idx & 127;
    float w = W[idx];
    unsigned short h = f2bf(w);
    unsigned short l = f2bf(w - bf2f(h));
    whi[n * K + k] = h;
    wlo[n * K + k] = l;
}

// ---------------------------------------------------------------------------
// Phase 1: counting sort by dst + gather-sum
// ---------------------------------------------------------------------------

// 4 edges per thread via int4
__global__ __launch_bounds__(256) void hist_kernel(const int* __restrict__ dst,
                                                   int* __restrict__ cnt)
{
    int i = blockIdx.x * 256 + threadIdx.x;          // over N_EDGES/4 int4s
    if (i < N_EDGES / 4) {
        int4 d = ((const int4*)dst)[i];
        atomicAdd(&cnt[d.x], 1);
        atomicAdd(&cnt[d.y], 1);
        atomicAdd(&cnt[d.z], 1);
        atomicAdd(&cnt[d.w], 1);
    }
}

__global__ __launch_bounds__(1024) void scan_reduce_kernel(const int* __restrict__ cnt,
                                                           int* __restrict__ btot)
{
    __shared__ int wsum[16];
    int t = threadIdx.x, lane = t & 63, w = t >> 6;
    int i = blockIdx.x * 1024 + t;
    int v = (i < N_NODES) ? cnt[i] : 0;
    #pragma unroll
    for (int off = 32; off > 0; off >>= 1) v += __shfl_xor(v, off);
    if (lane == 0) wsum[w] = v;
    __syncthreads();
    if (w == 0) {
        int s = (lane < 16) ? wsum[lane] : 0;
        #pragma unroll
        for (int off = 32; off > 0; off >>= 1) s += __shfl_xor(s, off);
        if (lane == 0) btot[blockIdx.x] = s;
    }
}

// spine fused in: wave 0 redundantly scans btot[0..N_TILES) per block
__global__ __launch_bounds__(1024) void scan_apply_kernel(int* __restrict__ cnt,
                                                          const int* __restrict__ btot)
{
    __shared__ int wsum[16];
    __shared__ int base_s;
    int t = threadIdx.x, lane = t & 63, w = t >> 6;

    if (t < 64) {
        int v = (t < N_TILES) ? btot[t] : 0;
        int x = v;
        #pragma unroll
        for (int off = 1; off < 64; off <<= 1) {
            int u = __shfl_up(x, off);
            if (lane >= off) x += u;
        }
        if (t == blockIdx.x) base_s = x - v;   // exclusive prefix of btot for this block
    }

    int i = blockIdx.x * 1024 + t;
    int v = (i < N_NODES) ? cnt[i] : 0;
    int x = v;
    #pragma unroll
    for (int off = 1; off < 64; off <<= 1) {
        int u = __shfl_up(x, off);
        if (lane >= off) x += u;
    }
    if (lane == 63) wsum[w] = x;
    __syncthreads();
    if (w == 0) {
        int s = (lane < 16) ? wsum[lane] : 0;
        #pragma unroll
        for (int off = 1; off < 16; off <<= 1) {
            int u = __shfl_up(s, off);
            if (lane >= off) s += u;
        }
        if (lane < 16) wsum[lane] = s;
    }
    __syncthreads();
    int base = base_s + ((w == 0) ? 0 : wsum[w - 1]);
    if (i < N_NODES) cnt[i] = base + (x - v);   // exclusive prefix
}

// 4 edges per thread; after this kernel offs[n] = end of node n's segment
__global__ __launch_bounds__(256) void reorder_kernel(const int* __restrict__ dst,
                                                      int* __restrict__ offs,
                                                      int* __restrict__ order)
{
    int i = blockIdx.x * 256 + threadIdx.x;
    if (i < N_EDGES / 4) {
        int4 d = ((const int4*)dst)[i];
        int e0 = i * 4;
        int p0 = atomicAdd(&offs[d.x], 1);
        int p1 = atomicAdd(&offs[d.y], 1);
        int p2 = atomicAdd(&offs[d.z], 1);
        int p3 = atomicAdd(&offs[d.w], 1);
        order[p0] = e0;
        order[p1] = e0 + 1;
        order[p2] = e0 + 2;
        order[p3] = e0 + 3;
    }
}

// one 64-lane wave per node; lane = channel; 8 rows in flight
__global__ __launch_bounds__(256) void gather_kernel(const float* __restrict__ ef,
                                                     const int* __restrict__ offs,
                                                     const int* __restrict__ order,
                                                     float* __restrict__ hn)
{
    int node = blockIdx.x * 4 + (threadIdx.x >> 6);
    int lane = threadIdx.x & 63;
    if (node >= N_NODES) return;
    int s = (node == 0) ? 0 : offs[node - 1];
    int e = offs[node];
    float a[8];
    #pragma unroll
    for (int k = 0; k < 8; ++k) a[k] = 0.f;

    int j = s;
    for (; j + 8 <= e; j += 8) {
        int idx[8];
        #pragma unroll
        for (int k = 0; k < 8; ++k) idx[k] = order[j + k];     // 8 independent loads
        #pragma unroll
        for (int k = 0; k < 8; ++k)
            a[k] += __builtin_nontemporal_load(ef + (size_t)idx[k] * 64 + lane);
    }
    for (; j < e; ++j)
        a[0] += __builtin_nontemporal_load(ef + (size_t)order[j] * 64 + lane);

    float r = ((a[0] + a[1]) + (a[2] + a[3])) + ((a[4] + a[5]) + (a[6] + a[7]));
    hn[(size_t)node * 64 + lane] = r;
}

// ---------------------------------------------------------------------------
// Phase 2: fused MLP via split-bf16 MFMA (16x16x32), 64 nodes/block, 4 waves.
// ---------------------------------------------------------------------------

__device__ __forceinline__ void stage_x(short* Xhi, short* Xlo,
                                        const float* __restrict__ g,
                                        int node0, int k0, int t)
{
    #pragma unroll
    for (int rep = 0; rep < 4; ++rep) {
        int idx  = rep * 256 + t;
        int node = idx >> 4;
        int kq   = idx & 15;
        int gn   = node0 + node;
        float4 v = make_float4(0.f, 0.f, 0.f, 0.f);
        if (gn < N_NODES) v = *(const float4*)(g + (size_t)gn * 64 + kq * 4);
        unsigned short h0 = f2bf(v.x), h1 = f2bf(v.y), h2 = f2bf(v.z), h3 = f2bf(v.w);
        bf16x4_t hv = {(short)h0, (short)h1, (short)h2, (short)h3};
        bf16x4_t lv = {(short)f2bf(v.x - bf2f(h0)), (short)f2bf(v.y - bf2f(h1)),
                       (short)f2bf(v.z - bf2f(h2)), (short)f2bf(v.w - bf2f(h3))};
        *(bf16x4_t*)(&Xhi[node * XS + k0 + kq * 4]) = hv;
        *(bf16x4_t*)(&Xlo[node * XS + k0 + kq * 4]) = lv;
    }
}

template <int KTOT, bool FINAL>
__device__ __forceinline__ void mfma_linear(short* Xhi, short* Xlo,
    const unsigned short* __restrict__ whi, const unsigned short* __restrict__ wlo,
    const float* __restrict__ bias, float* __restrict__ out, int node0, int t)
{
    const int lane = t & 63, wv = t >> 6, quad = lane >> 4, l15 = lane & 15;
    const int chb = wv * 32;

    f32x4_t acc[4][2];
    #pragma unroll
    for (int mt = 0; mt < 4; ++mt) {
        acc[mt][0] = (f32x4_t){0.f, 0.f, 0.f, 0.f};
        acc[mt][1] = (f32x4_t){0.f, 0.f, 0.f, 0.f};
    }
    float bv0 = bias[chb + l15];
    float bv1 = bias[chb + 16 + l15];

    const unsigned short* w0h = whi + (size_t)(chb + l15) * KTOT;
    const unsigned short* w0l = wlo + (size_t)(chb + l15) * KTOT;
    const unsigned short* w1h = whi + (size_t)(chb + 16 + l15) * KTOT;
    const unsigned short* w1l = wlo + (size_t)(chb + 16 + l15) * KTOT;

    #pragma unroll
    for (int ks = 0; ks < KTOT / 32; ++ks) {
        int kk = ks * 32 + quad * 8;
        bf16x8_t b0h = *(const bf16x8_t*)(w0h + kk);
        bf16x8_t b0l = *(const bf16x8_t*)(w0l + kk);
        bf16x8_t b1h = *(const bf16x8_t*)(w1h + kk);
        bf16x8_t b1l = *(const bf16x8_t*)(w1l + kk);
        #pragma unroll
        for (int mt = 0; mt < 4; ++mt) {
            bf16x8_t ah = *(const bf16x8_t*)(&Xhi[(mt * 16 + l15) * XS + kk]);
            bf16x8_t al = *(const bf16x8_t*)(&Xlo[(mt * 16 + l15) * XS + kk]);
            acc[mt][0] = __builtin_amdgcn_mfma_f32_16x16x32_bf16(ah, b0h, acc[mt][0], 0, 0, 0);
            acc[mt][0] = __builtin_amdgcn_mfma_f32_16x16x32_bf16(al, b0h, acc[mt][0], 0, 0, 0);
            acc[mt][0] = __builtin_amdgcn_mfma_f32_16x16x32_bf16(ah, b0l, acc[mt][0], 0, 0, 0);
            acc[mt][1] = __builtin_amdgcn_mfma_f32_16x16x32_bf16(ah, b1h, acc[mt][1], 0, 0, 0);
            acc[mt][1] = __builtin_amdgcn_mfma_f32_16x16x32_bf16(al, b1h, acc[mt][1], 0, 0, 0);
            acc[mt][1] = __builtin_amdgcn_mfma_f32_16x16x32_bf16(ah, b1l, acc[mt][1], 0, 0, 0);
        }
    }

    __syncthreads();

    if (!FINAL) {
        #pragma unroll
        for (int mt = 0; mt < 4; ++mt) {
            #pragma unroll
            for (int nt = 0; nt < 2; ++nt) {
                float bb = nt ? bv1 : bv0;
                int ch = chb + nt * 16 + l15;
                #pragma unroll
                for (int r = 0; r < 4; ++r) {
                    float y = fmaxf(acc[mt][nt][r] + bb, 0.f);
                    unsigned short h = f2bf(y);
                    unsigned short l = f2bf(y - bf2f(h));
                    int m = mt * 16 + quad * 4 + r;
                    Xhi[m * XS + ch] = (short)h;
                    Xlo[m * XS + ch] = (short)l;
                }
            }
        }
        __syncthreads();
    } else {
        #pragma unroll
        for (int mt = 0; mt < 4; ++mt) {
            #pragma unroll
            for (int nt = 0; nt < 2; ++nt) {
                float bb = nt ? bv1 : bv0;
                int ch = chb + nt * 16 + l15;
                #pragma unroll
                for (int r = 0; r < 4; ++r) {
                    int gn = node0 + mt * 16 + quad * 4 + r;
                    if (gn < N_NODES)
                        out[(size_t)gn * 128 + ch] = fmaxf(acc[mt][nt][r] + bb, 0.f);
                }
            }
        }
    }
}

__global__ __launch_bounds__(256) void gin_mlp_mfma_kernel(
    const float* __restrict__ nfeats, const float* __restrict__ hneigh,
    const unsigned short* __restrict__ wbuf,
    const float* __restrict__ b1_0, const float* __restrict__ b2_0,
    const float* __restrict__ b1_1, const float* __restrict__ b2_1,
    float* __restrict__ out)
{
    __shared__ short Xhi[NT * XS];
    __shared__ short Xlo[NT * XS];
    const int t = threadIdx.x;
    const int node0 = blockIdx.x * NT;

    stage_x(Xhi, Xlo, nfeats, node0, 0, t);
    stage_x(Xhi, Xlo, hneigh, node0, 64, t);
    stage_x(Xhi, Xlo, hneigh, node0, 128, t);
    __syncthreads();

    mfma_linear<128, false>(Xhi, Xlo, wbuf,          wbuf + 16384,  b1_0, nullptr, node0, t);
    mfma_linear<128, false>(Xhi, Xlo, wbuf + 32768,  wbuf + 49152,  b2_0, nullptr, node0, t);
    mfma_linear<192, false>(Xhi, Xlo, wbuf + 65536,  wbuf + 90112,  b1_1, nullptr, node0, t);
    mfma_linear<128, true >(Xhi, Xlo, wbuf + 114688, wbuf + 131072, b2_1, out,     node0, t);
}

// ---------------------------------------------------------------------------
extern "C" void kernel_launch(void* const* d_in, const int* in_sizes, int n_in,
                              void* d_out, int out_size, void* d_ws, size_t ws_size,
                              hipStream_t stream)
{
    const float* nfeats = (const float*)d_in[0];
    const float* efeats = (const float*)d_in[1];
    const int*   dst    = (const int*)d_in[2];
    const float* W1_0   = (const float*)d_in[3];
    const float* b1_0   = (const float*)d_in[4];
    const float* W2_0   = (const float*)d_in[5];
    const float* b2_0   = (const float*)d_in[6];
    const float* W1_1   = (const float*)d_in[7];
    const float* b1_1   = (const float*)d_in[8];
    const float* W2_1   = (const float*)d_in[9];
    const float* b2_1   = (const float*)d_in[10];
    float* out = (float*)d_out;

    char* ws = (char*)d_ws;
    float*          hneigh = (float*)ws;                       // 12,800,000 B
    int*            offs   = (int*)(ws + 12800000);            // 200,000 B (+pad)
    int*            order  = (int*)(ws + 13000192);            // 3,200,000 B
    int*            btot   = (int*)(ws + 16200192);            // 256 B
    unsigned short* wbuf   = (unsigned short*)(ws + 16200448); // 294,912 B

    hipMemsetAsync(offs, 0, N_NODES * sizeof(int), stream);

    prep_w_kernel<<<288, 256, 0, stream>>>(W1_0, W2_0, W1_1, W2_1, wbuf);

    hist_kernel<<<(N_EDGES / 4 + 255) / 256, 256, 0, stream>>>(dst, offs);
    scan_reduce_kernel<<<N_TILES, 1024, 0, stream>>>(offs, btot);
    scan_apply_kernel<<<N_TILES, 1024, 0, stream>>>(offs, btot);
    reorder_kernel<<<(N_EDGES / 4 + 255) / 256, 256, 0, stream>>>(dst, offs, order);
    gather_kernel<<<(N_NODES + 3) / 4, 256, 0, stream>>>(efeats, offs, order, hneigh);

    int nblk = (N_NODES + NT - 1) / NT;   // 782
    gin_mlp_mfma_kernel<<<nblk, 256, 0, stream>>>(
        nfeats, hneigh, wbuf, b1_0, b2_0, b1_1, b2_1, out);
}